// Round 1
// baseline (1774.748 us; speedup 1.0000x reference)
//
#include <hip/hip_runtime.h>
#include <math.h>

#define BB 4
#define LL 4096
#define CC 768
#define KHH 7
#define PADK 3
#define ROWS (BB*LL)      // 16384
#define NKP  (BB*KHH*LL)  // 114688

// ---------------- K1: layernorm + gate ----------------
__global__ __launch_bounds__(256) void k_ln(const float* __restrict__ x,
        const float* __restrict__ mask, const float* __restrict__ special,
        const float* __restrict__ lnw, const float* __restrict__ lnb,
        float* __restrict__ h, float* __restrict__ gate) {
    int row = blockIdx.x;
    const float* xr = x + (size_t)row * CC;
    float s = 0.f, q = 0.f;
    for (int i = threadIdx.x; i < CC; i += 256) { float v = xr[i]; s += v; q += v * v; }
    for (int o = 32; o; o >>= 1) { s += __shfl_xor(s, o); q += __shfl_xor(q, o); }
    __shared__ float ss[4], sq[4];
    int wid = threadIdx.x >> 6;
    if ((threadIdx.x & 63) == 0) { ss[wid] = s; sq[wid] = q; }
    __syncthreads();
    s = ss[0] + ss[1] + ss[2] + ss[3];
    q = sq[0] + sq[1] + sq[2] + sq[3];
    float mu  = s * (1.f / CC);
    float var = fmaxf(q * (1.f / CC) - mu * mu, 0.f);
    float rstd = rsqrtf(var + 1e-12f);
    float* hr = h + (size_t)row * CC;
    for (int i = threadIdx.x; i < CC; i += 256)
        hr[i] = (xr[i] - mu) * rstd * lnw[i] + lnb[i];
    if (threadIdx.x == 0) gate[row] = (1.f - special[row]) * mask[row];
}

// ---------------- K2: transpose reg_w[o][c][k] -> Wt[k][c][o] ----------------
__global__ __launch_bounds__(256) void k_wt(const float* __restrict__ rw, float* __restrict__ wt) {
    __shared__ float tile[64][65];
    int c0 = blockIdx.x * 64, o0 = blockIdx.y * 64;
    for (int k = 0; k < KHH; ++k) {
        int ci = threadIdx.x & 63, oi0 = (threadIdx.x >> 6) * 16;
        for (int s = 0; s < 16; ++s)
            tile[ci][oi0 + s] = rw[(size_t)(o0 + oi0 + s) * (CC * KHH) + (size_t)(c0 + ci) * KHH + k];
        __syncthreads();
        int oi = threadIdx.x & 63, ci0 = (threadIdx.x >> 6) * 16;
        for (int s = 0; s < 16; ++s)
            wt[(size_t)k * CC * CC + (size_t)(c0 + ci0 + s) * CC + (o0 + oi)] = tile[ci0 + s][oi];
        __syncthreads();
    }
}

// ---------------- K2b: conv weights -> Wc[c][128] (cols: conv*49 + k*7 + j, zero-padded) ----------------
__global__ __launch_bounds__(128) void k_wc(const float* __restrict__ ow, const float* __restrict__ mw,
                                            float* __restrict__ wc) {
    int c = blockIdx.x, i = threadIdx.x;
    float v = 0.f;
    if (i < 49)      v = ow[(size_t)(i / 7) * (CC * KHH) + (size_t)c * KHH + (i % 7)];
    else if (i < 98) { int j = i - 49; v = mw[(size_t)(j / 7) * (CC * KHH) + (size_t)c * KHH + (j % 7)]; }
    wc[c * 128 + i] = v;
}

// ---------------- K3: d[row][i] = sum_c h[row][c] * Wc[c][i]  (GEMM 16384 x 98pad128 x 768) ----------------
__global__ __launch_bounds__(256) void k_dg(const float* __restrict__ h, const float* __restrict__ wc,
                                            float* __restrict__ d) {
    __shared__ float As[32][36];
    __shared__ float Bs[32][128];
    int r0g = blockIdx.x * 32;
    int t = threadIdx.x;
    float acc[2][8];
#pragma unroll
    for (int u = 0; u < 2; ++u)
#pragma unroll
        for (int v = 0; v < 8; ++v) acc[u][v] = 0.f;
    int i0 = (t & 15) * 8, r0 = (t >> 4) * 2;
    for (int cc = 0; cc < CC; cc += 32) {
        { int r = t >> 3, ci4 = (t & 7) * 4;
          *(float4*)&As[r][ci4] = *(const float4*)(h + (size_t)(r0g + r) * CC + cc + ci4); }
#pragma unroll
        for (int s = 0; s < 4; ++s) {
            int flat = (s * 256 + t) * 4;
            int c = flat >> 7, i4 = flat & 127;
            *(float4*)&Bs[c][i4] = *(const float4*)(wc + (size_t)(cc + c) * 128 + i4);
        }
        __syncthreads();
#pragma unroll 8
        for (int ci = 0; ci < 32; ++ci) {
            float a0 = As[r0][ci], a1 = As[r0 + 1][ci];
            float4 b0 = *(float4*)&Bs[ci][i0];
            float4 b1 = *(float4*)&Bs[ci][i0 + 4];
            float bv[8] = {b0.x, b0.y, b0.z, b0.w, b1.x, b1.y, b1.z, b1.w};
#pragma unroll
            for (int v = 0; v < 8; ++v) {
                acc[0][v] = fmaf(a0, bv[v], acc[0][v]);
                acc[1][v] = fmaf(a1, bv[v], acc[1][v]);
            }
        }
        __syncthreads();
    }
#pragma unroll
    for (int u = 0; u < 2; ++u) {
        float4 v0 = {acc[u][0], acc[u][1], acc[u][2], acc[u][3]};
        float4 v1 = {acc[u][4], acc[u][5], acc[u][6], acc[u][7]};
        float* dr = d + (size_t)(r0g + r0 + u) * 128 + i0;
        *(float4*)dr = v0;
        *(float4*)(dr + 4) = v1;
    }
}

// ---------------- K4: finalize offsets/modulation -> sampling params ----------------
__global__ __launch_bounds__(256) void k_off(const float* __restrict__ d,
        const float* __restrict__ offb, const float* __restrict__ modb,
        const float* __restrict__ gate,
        int* __restrict__ idx0, int* __restrict__ idx1,
        float* __restrict__ w0a, float* __restrict__ w1a) {
    int flat = blockIdx.x * 256 + threadIdx.x;   // b*7*L + k*L + p
    if (flat >= NKP) return;
    int p = flat & (LL - 1);
    int k = (flat >> 12) % KHH;
    int b = flat / (KHH * LL);
    float offa = offb[k], moda = modb[k];
#pragma unroll
    for (int j = 0; j < KHH; ++j) {
        int q = p + j - PADK;
        if (q >= 0 && q < LL) {
            const float* dr = d + (size_t)(b * LL + q) * 128;
            offa += dr[k * 7 + j];
            moda += dr[49 + k * 7 + j];
        }
    }
    float modv = 2.f / (1.f + expf(-moda));
    float pos = (float)(p - PADK + k) + offa;
    pos = fminf(fmaxf(pos, -1.0e9f), 1.0e9f);
    float f = floorf(pos);
    float tf = pos - f;
    int i0 = (int)f;
    int i1 = i0 + 1;
    float in0 = (i0 >= 0 && i0 < LL) ? 1.f : 0.f;
    float in1 = (i1 >= 0 && i1 < LL) ? 1.f : 0.f;
    int c0 = min(max(i0, 0), LL - 1);
    int c1 = min(max(i1, 0), LL - 1);
    float g0 = gate[b * LL + c0] * in0;
    float g1 = gate[b * LL + c1] * in1;
    w0a[flat] = modv * (1.f - tf) * g0;
    w1a[flat] = modv * tf * g1;
    idx0[flat] = c0;
    idx1[flat] = c1;
}

// ---------------- K5: out[row][o] = resid + sum_{k,c} A[row][k,c] * Wt[k][c][o] ----------------
// BM=128, BN=128, BK=64; 256 threads; thread tile 8x8 (two 4-quads per dim)
__global__ __launch_bounds__(256) void k_main(const float* __restrict__ h, const float* __restrict__ wt,
        const int* __restrict__ idx0, const int* __restrict__ idx1,
        const float* __restrict__ w0a, const float* __restrict__ w1a,
        const float* __restrict__ resid, float* __restrict__ out) {
    __shared__ float As[64][128];   // [ci][r]  c-major
    __shared__ float Bs[64][128];   // [ci][o]
    int o0 = blockIdx.x * 128;
    int bt = blockIdx.y;            // 0..127
    int b = bt >> 5;                // 32 row-tiles per batch
    int p0 = (bt & 31) * 128;
    int t = threadIdx.x;
    int tcol = t & 15, trow = t >> 4;
    int rstage = t & 127;           // staging row owned by this thread
    int chalf = (t >> 7) * 32;      // staging c-half
    float acc[8][8];
#pragma unroll
    for (int u = 0; u < 8; ++u)
#pragma unroll
        for (int v = 0; v < 8; ++v) acc[u][v] = 0.f;

    for (int k = 0; k < KHH; ++k) {
        // per-thread sampling params for its staging row
        int pflat = ((b * KHH + k) << 12) + p0 + rstage;
        int gi0 = idx0[pflat], gi1 = idx1[pflat];
        float wa = w0a[pflat], wb = w1a[pflat];
        const float* h0base = h + (size_t)(b * LL + gi0) * CC;
        const float* h1base = h + (size_t)(b * LL + gi1) * CC;
        const float* wk = wt + (size_t)k * CC * CC;
        for (int cc = 0; cc < CC; cc += 64) {
            // stage A (gathered, lerp+mod folded): As[ci][r]
#pragma unroll
            for (int s = 0; s < 8; ++s) {
                int ci = chalf + s * 4;
                float4 va = *(const float4*)(h0base + cc + ci);
                float4 vb = *(const float4*)(h1base + cc + ci);
                As[ci + 0][rstage] = fmaf(wa, va.x, wb * vb.x);
                As[ci + 1][rstage] = fmaf(wa, va.y, wb * vb.y);
                As[ci + 2][rstage] = fmaf(wa, va.z, wb * vb.z);
                As[ci + 3][rstage] = fmaf(wa, va.w, wb * vb.w);
            }
            // stage B
#pragma unroll
            for (int s = 0; s < 8; ++s) {
                int flat4 = (s * 256 + t) * 4;
                int ci = flat4 >> 7, oi = flat4 & 127;
                *(float4*)&Bs[ci][oi] = *(const float4*)(wk + (size_t)(cc + ci) * CC + o0 + oi);
            }
            __syncthreads();
#pragma unroll 4
            for (int ci = 0; ci < 64; ++ci) {
                float4 a0 = *(float4*)&As[ci][trow * 4];
                float4 a1 = *(float4*)&As[ci][64 + trow * 4];
                float4 b0 = *(float4*)&Bs[ci][tcol * 4];
                float4 b1 = *(float4*)&Bs[ci][64 + tcol * 4];
                float av[8] = {a0.x, a0.y, a0.z, a0.w, a1.x, a1.y, a1.z, a1.w};
                float bv[8] = {b0.x, b0.y, b0.z, b0.w, b1.x, b1.y, b1.z, b1.w};
#pragma unroll
                for (int u = 0; u < 8; ++u)
#pragma unroll
                    for (int v = 0; v < 8; ++v)
                        acc[u][v] = fmaf(av[u], bv[v], acc[u][v]);
            }
            __syncthreads();
        }
    }
    // epilogue: + residual, write out
#pragma unroll
    for (int u = 0; u < 8; ++u) {
        int r = (u >> 2) * 64 + trow * 4 + (u & 3);
        size_t rowoff = ((size_t)(b * LL + p0 + r)) * CC + o0;
#pragma unroll
        for (int vq = 0; vq < 2; ++vq) {
            int col = vq * 64 + tcol * 4;
            float4 rv = *(const float4*)(resid + rowoff + col);
            float4 ov;
            ov.x = acc[u][vq * 4 + 0] + rv.x;
            ov.y = acc[u][vq * 4 + 1] + rv.y;
            ov.z = acc[u][vq * 4 + 2] + rv.z;
            ov.w = acc[u][vq * 4 + 3] + rv.w;
            *(float4*)(out + rowoff + col) = ov;
        }
    }
}

extern "C" void kernel_launch(void* const* d_in, const int* in_sizes, int n_in,
                              void* d_out, int out_size, void* d_ws, size_t ws_size,
                              hipStream_t stream) {
    const float* x   = (const float*)d_in[0];
    const float* am  = (const float*)d_in[1];
    const float* stm = (const float*)d_in[2];
    const float* lnw = (const float*)d_in[3];
    const float* lnb = (const float*)d_in[4];
    const float* ow  = (const float*)d_in[5];
    const float* ob  = (const float*)d_in[6];
    const float* mw  = (const float*)d_in[7];
    const float* mb  = (const float*)d_in[8];
    const float* rw  = (const float*)d_in[9];
    float* out = (float*)d_out;

    char* ws = (char*)d_ws;
    size_t off = 0;
    auto carve = [&](size_t bytes) -> char* {
        char* p = ws + off;
        off += (bytes + 255) & ~(size_t)255;
        return p;
    };
    float* h    = (float*)carve((size_t)ROWS * CC * 4);      // 50.3 MB
    float* wt   = (float*)carve((size_t)KHH * CC * CC * 4);  // 16.5 MB
    float* wc   = (float*)carve((size_t)CC * 128 * 4);       // 0.39 MB
    float* d    = (float*)carve((size_t)ROWS * 128 * 4);     // 8.4 MB
    float* gate = (float*)carve((size_t)ROWS * 4);
    int*   i0   = (int*)carve((size_t)NKP * 4);
    int*   i1   = (int*)carve((size_t)NKP * 4);
    float* w0   = (float*)carve((size_t)NKP * 4);
    float* w1   = (float*)carve((size_t)NKP * 4);

    k_ln<<<ROWS, 256, 0, stream>>>(x, am, stm, lnw, lnb, h, gate);
    k_wt<<<dim3(12, 12), 256, 0, stream>>>(rw, wt);
    k_wc<<<CC, 128, 0, stream>>>(ow, mw, wc);
    k_dg<<<ROWS / 32, 256, 0, stream>>>(h, wc, d);
    k_off<<<NKP / 256, 256, 0, stream>>>(d, ob, mb, gate, i0, i1, w0, w1);
    k_main<<<dim3(6, 128), 256, 0, stream>>>(h, wt, i0, i1, w0, w1, x, out);
}

// Round 2
// 400.868 us; speedup vs baseline: 4.4273x; 4.4273x over previous
//
#include <hip/hip_runtime.h>
#include <math.h>

#define BB 4
#define LL 4096
#define CC 768
#define KHH 7
#define PADK 3
#define ROWS (BB*LL)      // 16384
#define NKP  (BB*KHH*LL)  // 114688
#define GK   (KHH*CC)     // 5376

typedef unsigned short ushort8 __attribute__((ext_vector_type(8)));
typedef short short8 __attribute__((ext_vector_type(8)));
typedef float f32x4 __attribute__((ext_vector_type(4)));

__device__ __forceinline__ float bf2f(unsigned short u) {
    return __uint_as_float(((unsigned)u) << 16);
}
__device__ __forceinline__ unsigned short f2bf(float x) {
    unsigned u = __float_as_uint(x);
    return (unsigned short)((u + 0x7FFFu + ((u >> 16) & 1u)) >> 16);
}

// ---------------- K1: layernorm + gate -> h_bf16 ----------------
__global__ __launch_bounds__(256) void k_ln(const float* __restrict__ x,
        const float* __restrict__ mask, const float* __restrict__ special,
        const float* __restrict__ lnw, const float* __restrict__ lnb,
        unsigned short* __restrict__ hb, float* __restrict__ gate) {
    int row = blockIdx.x;
    const float* xr = x + (size_t)row * CC;
    float s = 0.f, q = 0.f;
    for (int i = threadIdx.x; i < CC; i += 256) { float v = xr[i]; s += v; q += v * v; }
    for (int o = 32; o; o >>= 1) { s += __shfl_xor(s, o); q += __shfl_xor(q, o); }
    __shared__ float ss[4], sq[4];
    int wid = threadIdx.x >> 6;
    if ((threadIdx.x & 63) == 0) { ss[wid] = s; sq[wid] = q; }
    __syncthreads();
    s = ss[0] + ss[1] + ss[2] + ss[3];
    q = sq[0] + sq[1] + sq[2] + sq[3];
    float mu  = s * (1.f / CC);
    float var = fmaxf(q * (1.f / CC) - mu * mu, 0.f);
    float rstd = rsqrtf(var + 1e-12f);
    unsigned short* hr = hb + (size_t)row * CC;
    for (int i = threadIdx.x; i < CC; i += 256)
        hr[i] = f2bf((xr[i] - mu) * rstd * lnw[i] + lnb[i]);
    if (threadIdx.x == 0) gate[row] = (1.f - special[row]) * mask[row];
}

// ---------------- K2: reg_w[o][c][k] -> Wb[o][k*768+c] bf16 ----------------
__global__ __launch_bounds__(256) void k_wb(const float* __restrict__ rw,
                                            unsigned short* __restrict__ wb) {
    __shared__ float s[GK];
    int o = blockIdx.x;
    for (int i = threadIdx.x; i < GK; i += 256) s[i] = rw[(size_t)o * GK + i];
    __syncthreads();
    unsigned short* orow = wb + (size_t)o * GK;
    for (int f = threadIdx.x; f < GK; f += 256) {
        int k = f / CC, c = f - k * CC;
        orow[f] = f2bf(s[c * KHH + k]);
    }
}

// ---------------- K2b: conv weights -> Wc[c][128] ----------------
__global__ __launch_bounds__(128) void k_wc(const float* __restrict__ ow, const float* __restrict__ mw,
                                            float* __restrict__ wc) {
    int c = blockIdx.x, i = threadIdx.x;
    float v = 0.f;
    if (i < 49)      v = ow[(size_t)(i / 7) * (CC * KHH) + (size_t)c * KHH + (i % 7)];
    else if (i < 98) { int j = i - 49; v = mw[(size_t)(j / 7) * (CC * KHH) + (size_t)c * KHH + (j % 7)]; }
    wc[c * 128 + i] = v;
}

// ---------------- K3: d[row][i] = sum_c hb[row][c] * Wc[c][i] ----------------
__global__ __launch_bounds__(256) void k_dg(const unsigned short* __restrict__ hb,
                                            const float* __restrict__ wc,
                                            float* __restrict__ d) {
    __shared__ float As[32][36];
    __shared__ float Bs[32][128];
    int r0g = blockIdx.x * 32;
    int t = threadIdx.x;
    float acc[2][8];
#pragma unroll
    for (int u = 0; u < 2; ++u)
#pragma unroll
        for (int v = 0; v < 8; ++v) acc[u][v] = 0.f;
    int i0 = (t & 15) * 8, r0 = (t >> 4) * 2;
    for (int cc = 0; cc < CC; cc += 32) {
        { int r = t >> 3, ci4 = (t & 7) * 4;
          unsigned long long v = *(const unsigned long long*)(hb + (size_t)(r0g + r) * CC + cc + ci4);
          As[r][ci4 + 0] = bf2f((unsigned short)(v & 0xFFFF));
          As[r][ci4 + 1] = bf2f((unsigned short)((v >> 16) & 0xFFFF));
          As[r][ci4 + 2] = bf2f((unsigned short)((v >> 32) & 0xFFFF));
          As[r][ci4 + 3] = bf2f((unsigned short)((v >> 48) & 0xFFFF)); }
#pragma unroll
        for (int s = 0; s < 4; ++s) {
            int flat = (s * 256 + t) * 4;
            int c = flat >> 7, i4 = flat & 127;
            *(float4*)&Bs[c][i4] = *(const float4*)(wc + (size_t)(cc + c) * 128 + i4);
        }
        __syncthreads();
#pragma unroll 8
        for (int ci = 0; ci < 32; ++ci) {
            float a0 = As[r0][ci], a1 = As[r0 + 1][ci];
            float4 b0 = *(float4*)&Bs[ci][i0];
            float4 b1 = *(float4*)&Bs[ci][i0 + 4];
            float bv[8] = {b0.x, b0.y, b0.z, b0.w, b1.x, b1.y, b1.z, b1.w};
#pragma unroll
            for (int v = 0; v < 8; ++v) {
                acc[0][v] = fmaf(a0, bv[v], acc[0][v]);
                acc[1][v] = fmaf(a1, bv[v], acc[1][v]);
            }
        }
        __syncthreads();
    }
#pragma unroll
    for (int u = 0; u < 2; ++u) {
        float4 v0 = {acc[u][0], acc[u][1], acc[u][2], acc[u][3]};
        float4 v1 = {acc[u][4], acc[u][5], acc[u][6], acc[u][7]};
        float* dr = d + (size_t)(r0g + r0 + u) * 128 + i0;
        *(float4*)dr = v0;
        *(float4*)(dr + 4) = v1;
    }
}

// ---------------- K4: sampling params ----------------
__global__ __launch_bounds__(256) void k_off(const float* __restrict__ d,
        const float* __restrict__ offb, const float* __restrict__ modb,
        const float* __restrict__ gate,
        int* __restrict__ idx0, int* __restrict__ idx1,
        float* __restrict__ w0a, float* __restrict__ w1a) {
    int flat = blockIdx.x * 256 + threadIdx.x;   // b*7*L + k*L + p
    if (flat >= NKP) return;
    int p = flat & (LL - 1);
    int k = (flat >> 12) % KHH;
    int b = flat / (KHH * LL);
    float offa = offb[k], moda = modb[k];
#pragma unroll
    for (int j = 0; j < KHH; ++j) {
        int q = p + j - PADK;
        if (q >= 0 && q < LL) {
            const float* dr = d + (size_t)(b * LL + q) * 128;
            offa += dr[k * 7 + j];
            moda += dr[49 + k * 7 + j];
        }
    }
    float modv = 2.f / (1.f + expf(-moda));
    float pos = (float)(p - PADK + k) + offa;
    pos = fminf(fmaxf(pos, -1.0e9f), 1.0e9f);
    float f = floorf(pos);
    float tf = pos - f;
    int i0 = (int)f;
    int i1 = i0 + 1;
    float in0 = (i0 >= 0 && i0 < LL) ? 1.f : 0.f;
    float in1 = (i1 >= 0 && i1 < LL) ? 1.f : 0.f;
    int c0 = min(max(i0, 0), LL - 1);
    int c1 = min(max(i1, 0), LL - 1);
    float g0 = gate[b * LL + c0] * in0;
    float g1 = gate[b * LL + c1] * in1;
    w0a[flat] = modv * (1.f - tf) * g0;
    w1a[flat] = modv * tf * g1;
    idx0[flat] = c0;
    idx1[flat] = c1;
}

// ---------------- K5: build sampled A matrix  Abf[row][k*768+c] bf16 ----------------
__global__ __launch_bounds__(256) void k_bld(const unsigned short* __restrict__ hb,
        const int* __restrict__ idx0, const int* __restrict__ idx1,
        const float* __restrict__ w0a, const float* __restrict__ w1a,
        unsigned short* __restrict__ Abf) {
    int row = blockIdx.x;
    int b = row >> 12, p = row & (LL - 1);
    __shared__ int sg0[KHH], sg1[KHH];
    __shared__ float sw0[KHH], sw1[KHH];
    if (threadIdx.x < KHH) {
        int pf = ((b * KHH + threadIdx.x) << 12) + p;
        sg0[threadIdx.x] = idx0[pf]; sg1[threadIdx.x] = idx1[pf];
        sw0[threadIdx.x] = w0a[pf];  sw1[threadIdx.x] = w1a[pf];
    }
    __syncthreads();
    unsigned short* orow = Abf + (size_t)row * GK;
    const size_t hbb = (size_t)b * LL * CC;
    for (int f = threadIdx.x; f < 672; f += 256) {
        int k = f / 96, c0 = (f - k * 96) * 8;
        ushort8 v0 = *(const ushort8*)(hb + hbb + (size_t)sg0[k] * CC + c0);
        ushort8 v1 = *(const ushort8*)(hb + hbb + (size_t)sg1[k] * CC + c0);
        float wa = sw0[k], wb = sw1[k];
        ushort8 r;
#pragma unroll
        for (int e = 0; e < 8; ++e)
            r[e] = f2bf(wa * bf2f(v0[e]) + wb * bf2f(v1[e]));
        *(ushort8*)(orow + k * CC + c0) = r;
    }
}

// ---------------- K6: bf16 MFMA GEMM: out[r][o] = resid + sum_K Abf[r][K]*Wb[o][K] ----------------
// BM=128, BN=128, BK=64; 256 threads = 4 waves (2x2), wave tile 64x64, 4x4 frags of 16x16x32
__global__ __launch_bounds__(256) void k_gemm(const unsigned short* __restrict__ A,
        const unsigned short* __restrict__ Bm,
        const float* __restrict__ resid, float* __restrict__ out) {
    __shared__ char As[128 * 128];   // 128 rows x 128 bytes (64 bf16), XOR-swizzled
    __shared__ char Bs[128 * 128];
    int o0 = blockIdx.x * 128;
    int r0 = blockIdx.y * 128;
    int t = threadIdx.x;
    int lane = t & 63, w = t >> 6;
    int wr = w >> 1, wc = w & 1;

    f32x4 acc[4][4];
#pragma unroll
    for (int m = 0; m < 4; ++m)
#pragma unroll
        for (int n = 0; n < 4; ++n) acc[m][n] = (f32x4){0.f, 0.f, 0.f, 0.f};

    int lr = lane & 15;
    int lkb0 = (lane >> 4) * 16;   // byte offset of k-chunk within row

    for (int kk = 0; kk < GK; kk += 64) {
        // stage A and B (reg-staged, swizzled ds_write_b128)
#pragma unroll
        for (int s = 0; s < 4; ++s) {
            int byteoff = (s * 256 + t) * 16;
            int row = byteoff >> 7;         // 0..127
            int colb = byteoff & 127;       // byte within row
            int sw = (row * 128 + colb) ^ ((row & 7) << 4);
            ushort8 va = *(const ushort8*)(A + (size_t)(r0 + row) * GK + kk + (colb >> 1));
            *(ushort8*)(As + sw) = va;
            ushort8 vb = *(const ushort8*)(Bm + (size_t)(o0 + row) * GK + kk + (colb >> 1));
            *(ushort8*)(Bs + sw) = vb;
        }
        __syncthreads();
#pragma unroll
        for (int ks = 0; ks < 2; ++ks) {
            short8 av[4], bv[4];
            int lkb = lkb0 + ks * 64;
#pragma unroll
            for (int m = 0; m < 4; ++m) {
                int ar = wr * 64 + m * 16 + lr;
                av[m] = *(const short8*)(As + ((ar * 128 + lkb) ^ ((ar & 7) << 4)));
            }
#pragma unroll
            for (int n = 0; n < 4; ++n) {
                int br = wc * 64 + n * 16 + lr;
                bv[n] = *(const short8*)(Bs + ((br * 128 + lkb) ^ ((br & 7) << 4)));
            }
#pragma unroll
            for (int m = 0; m < 4; ++m)
#pragma unroll
                for (int n = 0; n < 4; ++n)
                    acc[m][n] = __builtin_amdgcn_mfma_f32_16x16x32_bf16(av[m], bv[n], acc[m][n], 0, 0, 0);
        }
        __syncthreads();
    }
    // epilogue: + residual
    int lr4 = (lane >> 4) * 4, lc = lane & 15;
#pragma unroll
    for (int m = 0; m < 4; ++m) {
        int gr = r0 + wr * 64 + m * 16 + lr4;
#pragma unroll
        for (int n = 0; n < 4; ++n) {
            int gc = o0 + wc * 64 + n * 16 + lc;
#pragma unroll
            for (int j = 0; j < 4; ++j) {
                size_t idx = (size_t)(gr + j) * CC + gc;
                out[idx] = acc[m][n][j] + resid[idx];
            }
        }
    }
}

extern "C" void kernel_launch(void* const* d_in, const int* in_sizes, int n_in,
                              void* d_out, int out_size, void* d_ws, size_t ws_size,
                              hipStream_t stream) {
    const float* x   = (const float*)d_in[0];
    const float* am  = (const float*)d_in[1];
    const float* stm = (const float*)d_in[2];
    const float* lnw = (const float*)d_in[3];
    const float* lnb = (const float*)d_in[4];
    const float* ow  = (const float*)d_in[5];
    const float* ob  = (const float*)d_in[6];
    const float* mw  = (const float*)d_in[7];
    const float* mb  = (const float*)d_in[8];
    const float* rw  = (const float*)d_in[9];
    float* out = (float*)d_out;

    char* ws = (char*)d_ws;
    size_t off = 0;
    auto carve = [&](size_t bytes) -> char* {
        char* p = ws + off;
        off += (bytes + 255) & ~(size_t)255;
        return p;
    };
    unsigned short* hb  = (unsigned short*)carve((size_t)ROWS * CC * 2);   // 25.2 MB
    unsigned short* wb  = (unsigned short*)carve((size_t)CC * GK * 2);     // 8.25 MB
    float* wc   = (float*)carve((size_t)CC * 128 * 4);                     // 0.39 MB
    float* d    = (float*)carve((size_t)ROWS * 128 * 4);                   // 8.4 MB
    float* gate = (float*)carve((size_t)ROWS * 4);
    int*   i0   = (int*)carve((size_t)NKP * 4);
    int*   i1   = (int*)carve((size_t)NKP * 4);
    float* w0   = (float*)carve((size_t)NKP * 4);
    float* w1   = (float*)carve((size_t)NKP * 4);
    unsigned short* Abf = (unsigned short*)carve((size_t)ROWS * GK * 2);   // 176.2 MB

    k_ln<<<ROWS, 256, 0, stream>>>(x, am, stm, lnw, lnb, hb, gate);
    k_wb<<<CC, 256, 0, stream>>>(rw, wb);
    k_wc<<<CC, 128, 0, stream>>>(ow, mw, wc);
    k_dg<<<ROWS / 32, 256, 0, stream>>>(hb, wc, d);
    k_off<<<NKP / 256, 256, 0, stream>>>(d, ob, mb, gate, i0, i1, w0, w1);
    k_bld<<<ROWS, 256, 0, stream>>>(hb, i0, i1, w0, w1, Abf);
    k_gemm<<<dim3(6, 128), 256, 0, stream>>>(Abf, wb, x, out);
}

// Round 3
// 255.902 us; speedup vs baseline: 6.9353x; 1.5665x over previous
//
#include <hip/hip_runtime.h>
#include <math.h>

#define BB 4
#define LL 4096
#define CC 768
#define KHH 7
#define PADK 3
#define ROWS (BB*LL)      // 16384
#define NKP  (BB*KHH*LL)  // 114688
#define GK   (KHH*CC)     // 5376
#define NT   (GK/64)      // 84

typedef unsigned short ushort8 __attribute__((ext_vector_type(8)));
typedef short short8 __attribute__((ext_vector_type(8)));
typedef float f32x4 __attribute__((ext_vector_type(4)));

__device__ __forceinline__ float bf2f(unsigned short u) {
    return __uint_as_float(((unsigned)u) << 16);
}
__device__ __forceinline__ unsigned short f2bf(float x) {
    unsigned u = __float_as_uint(x);
    return (unsigned short)((u + 0x7FFFu + ((u >> 16) & 1u)) >> 16);
}

// ---------------- K1: layernorm + gate -> h_bf16 ----------------
__global__ __launch_bounds__(256) void k_ln(const float* __restrict__ x,
        const float* __restrict__ mask, const float* __restrict__ special,
        const float* __restrict__ lnw, const float* __restrict__ lnb,
        unsigned short* __restrict__ hb, float* __restrict__ gate) {
    int row = blockIdx.x;
    const float* xr = x + (size_t)row * CC;
    float s = 0.f, q = 0.f;
    for (int i = threadIdx.x; i < CC; i += 256) { float v = xr[i]; s += v; q += v * v; }
    for (int o = 32; o; o >>= 1) { s += __shfl_xor(s, o); q += __shfl_xor(q, o); }
    __shared__ float ss[4], sq[4];
    int wid = threadIdx.x >> 6;
    if ((threadIdx.x & 63) == 0) { ss[wid] = s; sq[wid] = q; }
    __syncthreads();
    s = ss[0] + ss[1] + ss[2] + ss[3];
    q = sq[0] + sq[1] + sq[2] + sq[3];
    float mu  = s * (1.f / CC);
    float var = fmaxf(q * (1.f / CC) - mu * mu, 0.f);
    float rstd = rsqrtf(var + 1e-12f);
    unsigned short* hr = hb + (size_t)row * CC;
    for (int i = threadIdx.x; i < CC; i += 256)
        hr[i] = f2bf((xr[i] - mu) * rstd * lnw[i] + lnb[i]);
    if (threadIdx.x == 0) gate[row] = (1.f - special[row]) * mask[row];
}

// ---------------- K2: reg_w[o][c][k] -> Wb[o][k*768+c] bf16 ----------------
__global__ __launch_bounds__(256) void k_wb(const float* __restrict__ rw,
                                            unsigned short* __restrict__ wb) {
    __shared__ float s[GK];
    int o = blockIdx.x;
    for (int i = threadIdx.x; i < GK; i += 256) s[i] = rw[(size_t)o * GK + i];
    __syncthreads();
    unsigned short* orow = wb + (size_t)o * GK;
    for (int f = threadIdx.x; f < GK; f += 256) {
        int k = f / CC, c = f - k * CC;
        orow[f] = f2bf(s[c * KHH + k]);
    }
}

// ---------------- K2b: conv weights -> wcb[i][c] bf16 (i = conv*49+k*7+j, padded to 128) ----------------
__global__ __launch_bounds__(256) void k_wcb(const float* __restrict__ ow, const float* __restrict__ mw,
                                             unsigned short* __restrict__ wcb) {
    int i = blockIdx.x;
    for (int c = threadIdx.x; c < CC; c += 256) {
        float v = 0.f;
        if (i < 49)      v = ow[(size_t)(i / 7) * (CC * KHH) + (size_t)c * KHH + (i % 7)];
        else if (i < 98) { int j = i - 49; v = mw[(size_t)(j / 7) * (CC * KHH) + (size_t)c * KHH + (j % 7)]; }
        wcb[(size_t)i * CC + c] = f2bf(v);
    }
}

// ---------------- K3: d[row][i] = sum_c hb[row][c] * wcb[i][c]  (bf16 MFMA, N=128, K=768) ----------------
__global__ __launch_bounds__(256) void k_dg2(const unsigned short* __restrict__ A,
        const unsigned short* __restrict__ Bm, float* __restrict__ d) {
    __shared__ __align__(16) char As[128 * 128];
    __shared__ __align__(16) char Bs[128 * 128];
    int r0 = blockIdx.x * 128;
    int t = threadIdx.x;
    int lane = t & 63, w = t >> 6;
    int wr = w >> 1, wc = w & 1;
    f32x4 acc[4][4];
#pragma unroll
    for (int m = 0; m < 4; ++m)
#pragma unroll
        for (int n = 0; n < 4; ++n) acc[m][n] = (f32x4){0.f, 0.f, 0.f, 0.f};
    int lr = lane & 15;
    int lkb0 = (lane >> 4) * 16;
    for (int kk = 0; kk < CC; kk += 64) {
#pragma unroll
        for (int s = 0; s < 4; ++s) {
            int byteoff = (s * 256 + t) * 16;
            int row = byteoff >> 7;
            int colb = byteoff & 127;
            int sw = (row * 128 + colb) ^ ((row & 7) << 4);
            *(ushort8*)(As + sw) = *(const ushort8*)(A + (size_t)(r0 + row) * CC + kk + (colb >> 1));
            *(ushort8*)(Bs + sw) = *(const ushort8*)(Bm + (size_t)row * CC + kk + (colb >> 1));
        }
        __syncthreads();
#pragma unroll
        for (int ks = 0; ks < 2; ++ks) {
            short8 av[4], bv[4];
            int lkb = lkb0 + ks * 64;
#pragma unroll
            for (int m = 0; m < 4; ++m) {
                int ar = wr * 64 + m * 16 + lr;
                av[m] = *(const short8*)(As + ((ar * 128 + lkb) ^ ((ar & 7) << 4)));
            }
#pragma unroll
            for (int n = 0; n < 4; ++n) {
                int br = wc * 64 + n * 16 + lr;
                bv[n] = *(const short8*)(Bs + ((br * 128 + lkb) ^ ((br & 7) << 4)));
            }
#pragma unroll
            for (int m = 0; m < 4; ++m)
#pragma unroll
                for (int n = 0; n < 4; ++n)
                    acc[m][n] = __builtin_amdgcn_mfma_f32_16x16x32_bf16(av[m], bv[n], acc[m][n], 0, 0, 0);
        }
        __syncthreads();
    }
    int lr4 = (lane >> 4) * 4, lc = lane & 15;
#pragma unroll
    for (int m = 0; m < 4; ++m) {
        int gr = r0 + wr * 64 + m * 16 + lr4;
#pragma unroll
        for (int n = 0; n < 4; ++n) {
            int gc = wc * 64 + n * 16 + lc;
#pragma unroll
            for (int j = 0; j < 4; ++j)
                d[(size_t)(gr + j) * 128 + gc] = acc[m][n][j];
        }
    }
}

// ---------------- K4: sampling params ----------------
__global__ __launch_bounds__(256) void k_off(const float* __restrict__ d,
        const float* __restrict__ offb, const float* __restrict__ modb,
        const float* __restrict__ gate,
        int* __restrict__ idx0, int* __restrict__ idx1,
        float* __restrict__ w0a, float* __restrict__ w1a) {
    int flat = blockIdx.x * 256 + threadIdx.x;   // b*7*L + k*L + p
    if (flat >= NKP) return;
    int p = flat & (LL - 1);
    int k = (flat >> 12) % KHH;
    int b = flat / (KHH * LL);
    float offa = offb[k], moda = modb[k];
#pragma unroll
    for (int j = 0; j < KHH; ++j) {
        int q = p + j - PADK;
        if (q >= 0 && q < LL) {
            const float* dr = d + (size_t)(b * LL + q) * 128;
            offa += dr[k * 7 + j];
            moda += dr[49 + k * 7 + j];
        }
    }
    float modv = 2.f / (1.f + expf(-moda));
    float pos = (float)(p - PADK + k) + offa;
    pos = fminf(fmaxf(pos, -1.0e9f), 1.0e9f);
    float f = floorf(pos);
    float tf = pos - f;
    int i0 = (int)f;
    int i1 = i0 + 1;
    float in0 = (i0 >= 0 && i0 < LL) ? 1.f : 0.f;
    float in1 = (i1 >= 0 && i1 < LL) ? 1.f : 0.f;
    int c0 = min(max(i0, 0), LL - 1);
    int c1 = min(max(i1, 0), LL - 1);
    float g0 = gate[b * LL + c0] * in0;
    float g1 = gate[b * LL + c1] * in1;
    w0a[flat] = modv * (1.f - tf) * g0;
    w1a[flat] = modv * tf * g1;
    idx0[flat] = c0;
    idx1[flat] = c1;
}

// ---------------- K5: fused sample+GEMM: out[r][o] = resid + sum_{k,c} lerp(hb) * Wb ----------------
// BM=128, BN=384, BK=64; 512 threads = 8 waves (2x4), wave tile 64x96 = 4x6 frags 16x16x32
// Double-buffered LDS; column-half chosen by XCD so each XCD's L2 holds one Wb half.
__global__ __launch_bounds__(512, 2) void k_fgemm(const unsigned short* __restrict__ hb,
        const unsigned short* __restrict__ Wb,
        const int* __restrict__ idx0, const int* __restrict__ idx1,
        const float* __restrict__ w0a, const float* __restrict__ w1a,
        const float* __restrict__ resid, float* __restrict__ out) {
    __shared__ __align__(16) char As[2][128 * 128];
    __shared__ __align__(16) char Bs[2][384 * 128];

    int bid = blockIdx.x;
    int nhalf = (bid & 7) >> 2;                 // XCDs 0-3 -> half 0, 4-7 -> half 1
    int rowtile = (bid >> 3) * 4 + (bid & 3);   // bijective 0..127
    int r0 = rowtile * 128;
    int o0 = nhalf * 384;
    int b = r0 >> 12;
    int p0 = r0 & (LL - 1);
    int pbase = ((b * KHH) << 12) + p0;
    const unsigned short* hbB = hb + (size_t)b * LL * CC;
    const unsigned short* wbase = Wb + (size_t)o0 * GK;

    int t = threadIdx.x;
    int lane = t & 63, w = t >> 6;
    int wr = w >> 2, wc = w & 3;

    // A-build mapping: row = t>>2 (0..127), seg = t&3 (16 elems each)
    int arow = t >> 2, aseg = t & 3;
    int acolb = aseg * 32;
    int aswz0 = arow * 128 + (acolb ^ ((arow & 7) << 4));
    int aswz1 = arow * 128 + ((acolb + 16) ^ ((arow & 7) << 4));

    f32x4 acc[4][6];
#pragma unroll
    for (int m = 0; m < 4; ++m)
#pragma unroll
        for (int n = 0; n < 6; ++n) acc[m][n] = (f32x4){0.f, 0.f, 0.f, 0.f};

    auto stage = [&](int tap, int c0, char* Asb, char* Bsb) {
        int pf = pbase + (tap << 12) + arow;
        int g0 = idx0[pf], g1 = idx1[pf];
        float wa = w0a[pf], wbv = w1a[pf];
        const unsigned short* s0 = hbB + (size_t)g0 * CC + c0 + aseg * 16;
        const unsigned short* s1 = hbB + (size_t)g1 * CC + c0 + aseg * 16;
        ushort8 v00 = *(const ushort8*)(s0);
        ushort8 v01 = *(const ushort8*)(s0 + 8);
        ushort8 v10 = *(const ushort8*)(s1);
        ushort8 v11 = *(const ushort8*)(s1 + 8);
        ushort8 ra, rb;
#pragma unroll
        for (int e = 0; e < 8; ++e) ra[e] = f2bf(fmaf(wa, bf2f(v00[e]), wbv * bf2f(v10[e])));
#pragma unroll
        for (int e = 0; e < 8; ++e) rb[e] = f2bf(fmaf(wa, bf2f(v01[e]), wbv * bf2f(v11[e])));
        *(ushort8*)(Asb + aswz0) = ra;
        *(ushort8*)(Asb + aswz1) = rb;
        // B stage: 384 rows x 64 k
        int kk = tap * CC + c0;
#pragma unroll
        for (int i = 0; i < 6; ++i) {
            int off = (i * 512 + t) * 16;
            int brow = off >> 7;
            int colb = off & 127;
            ushort8 v = *(const ushort8*)(wbase + (size_t)brow * GK + kk + (colb >> 1));
            *(ushort8*)(Bsb + (brow * 128 + (colb ^ ((brow & 7) << 4)))) = v;
        }
    };

    auto compute = [&](const char* Asb, const char* Bsb) {
        int lr = lane & 15;
        int lkb0 = (lane >> 4) * 16;
#pragma unroll
        for (int ks = 0; ks < 2; ++ks) {
            short8 av[4], bv[6];
            int lkb = lkb0 + ks * 64;
#pragma unroll
            for (int m = 0; m < 4; ++m) {
                int ar = wr * 64 + m * 16 + lr;
                av[m] = *(const short8*)(Asb + ar * 128 + (lkb ^ ((ar & 7) << 4)));
            }
#pragma unroll
            for (int n = 0; n < 6; ++n) {
                int br = wc * 96 + n * 16 + lr;
                bv[n] = *(const short8*)(Bsb + br * 128 + (lkb ^ ((br & 7) << 4)));
            }
#pragma unroll
            for (int m = 0; m < 4; ++m)
#pragma unroll
                for (int n = 0; n < 6; ++n)
                    acc[m][n] = __builtin_amdgcn_mfma_f32_16x16x32_bf16(av[m], bv[n], acc[m][n], 0, 0, 0);
        }
    };

    stage(0, 0, As[0], Bs[0]);
    __syncthreads();
    int tap_n = 0, c0_n = 0;
    for (int s = 0; s < NT; ++s) {
        int cur = s & 1;
        c0_n += 64;
        if (c0_n == CC) { c0_n = 0; ++tap_n; }
        if (s + 1 < NT) stage(tap_n, c0_n, As[cur ^ 1], Bs[cur ^ 1]);
        compute(As[cur], Bs[cur]);
        __syncthreads();
    }

    // epilogue: + residual
    int lr4 = (lane >> 4) * 4, lc = lane & 15;
#pragma unroll
    for (int m = 0; m < 4; ++m) {
        int gr = r0 + wr * 64 + m * 16 + lr4;
#pragma unroll
        for (int n = 0; n < 6; ++n) {
            int gc = o0 + wc * 96 + n * 16 + lc;
#pragma unroll
            for (int j = 0; j < 4; ++j) {
                size_t idx = (size_t)(gr + j) * CC + gc;
                out[idx] = acc[m][n][j] + resid[idx];
            }
        }
    }
}

extern "C" void kernel_launch(void* const* d_in, const int* in_sizes, int n_in,
                              void* d_out, int out_size, void* d_ws, size_t ws_size,
                              hipStream_t stream) {
    const float* x   = (const float*)d_in[0];
    const float* am  = (const float*)d_in[1];
    const float* stm = (const float*)d_in[2];
    const float* lnw = (const float*)d_in[3];
    const float* lnb = (const float*)d_in[4];
    const float* ow  = (const float*)d_in[5];
    const float* ob  = (const float*)d_in[6];
    const float* mw  = (const float*)d_in[7];
    const float* mb  = (const float*)d_in[8];
    const float* rw  = (const float*)d_in[9];
    float* out = (float*)d_out;

    char* ws = (char*)d_ws;
    size_t off = 0;
    auto carve = [&](size_t bytes) -> char* {
        char* p = ws + off;
        off += (bytes + 255) & ~(size_t)255;
        return p;
    };
    unsigned short* hb  = (unsigned short*)carve((size_t)ROWS * CC * 2);   // 25.2 MB
    unsigned short* wb  = (unsigned short*)carve((size_t)CC * GK * 2);     // 8.25 MB
    unsigned short* wcb = (unsigned short*)carve((size_t)128 * CC * 2);    // 0.20 MB
    float* d    = (float*)carve((size_t)ROWS * 128 * 4);                   // 8.4 MB
    float* gate = (float*)carve((size_t)ROWS * 4);
    int*   i0   = (int*)carve((size_t)NKP * 4);
    int*   i1   = (int*)carve((size_t)NKP * 4);
    float* w0   = (float*)carve((size_t)NKP * 4);
    float* w1   = (float*)carve((size_t)NKP * 4);

    k_ln<<<ROWS, 256, 0, stream>>>(x, am, stm, lnw, lnb, hb, gate);
    k_wb<<<CC, 256, 0, stream>>>(rw, wb);
    k_wcb<<<128, 256, 0, stream>>>(ow, mw, wcb);
    k_dg2<<<ROWS / 128, 256, 0, stream>>>(hb, wcb, d);
    k_off<<<NKP / 256, 256, 0, stream>>>(d, ob, mb, gate, i0, i1, w0, w1);
    k_fgemm<<<256, 512, 0, stream>>>(hb, wb, i0, i1, w0, w1, x, out);
}

// Round 4
// 216.585 us; speedup vs baseline: 8.1942x; 1.1815x over previous
//
#include <hip/hip_runtime.h>
#include <math.h>

#define BB 4
#define LL 4096
#define CC 768
#define KHH 7
#define PADK 3
#define ROWS (BB*LL)      // 16384
#define NKP  (BB*KHH*LL)  // 114688
#define GK   (KHH*CC)     // 5376
#define NT   (GK/64)      // 84

typedef unsigned short ushort8 __attribute__((ext_vector_type(8)));
typedef short short8 __attribute__((ext_vector_type(8)));
typedef float f32x4 __attribute__((ext_vector_type(4)));

__device__ __forceinline__ float bf2f(unsigned short u) {
    return __uint_as_float(((unsigned)u) << 16);
}
__device__ __forceinline__ unsigned short f2bf(float x) {
    unsigned u = __float_as_uint(x);
    return (unsigned short)((u + 0x7FFFu + ((u >> 16) & 1u)) >> 16);
}

// ---------------- K1: layernorm + gate -> h_bf16 ----------------
__global__ __launch_bounds__(256) void k_ln(const float* __restrict__ x,
        const float* __restrict__ mask, const float* __restrict__ special,
        const float* __restrict__ lnw, const float* __restrict__ lnb,
        unsigned short* __restrict__ hb, float* __restrict__ gate) {
    int row = blockIdx.x;
    const float* xr = x + (size_t)row * CC;
    float s = 0.f, q = 0.f;
    for (int i = threadIdx.x; i < CC; i += 256) { float v = xr[i]; s += v; q += v * v; }
    for (int o = 32; o; o >>= 1) { s += __shfl_xor(s, o); q += __shfl_xor(q, o); }
    __shared__ float ss[4], sq[4];
    int wid = threadIdx.x >> 6;
    if ((threadIdx.x & 63) == 0) { ss[wid] = s; sq[wid] = q; }
    __syncthreads();
    s = ss[0] + ss[1] + ss[2] + ss[3];
    q = sq[0] + sq[1] + sq[2] + sq[3];
    float mu  = s * (1.f / CC);
    float var = fmaxf(q * (1.f / CC) - mu * mu, 0.f);
    float rstd = rsqrtf(var + 1e-12f);
    unsigned short* hr = hb + (size_t)row * CC;
    for (int i = threadIdx.x; i < CC; i += 256)
        hr[i] = f2bf((xr[i] - mu) * rstd * lnw[i] + lnb[i]);
    if (threadIdx.x == 0) gate[row] = (1.f - special[row]) * mask[row];
}

// ---------------- K2: reg_w[o][c][k] -> Wb[o][k*768+c] bf16 ----------------
__global__ __launch_bounds__(256) void k_wb(const float* __restrict__ rw,
                                            unsigned short* __restrict__ wb) {
    __shared__ float s[GK];
    int o = blockIdx.x;
    for (int i = threadIdx.x; i < GK; i += 256) s[i] = rw[(size_t)o * GK + i];
    __syncthreads();
    unsigned short* orow = wb + (size_t)o * GK;
    for (int f = threadIdx.x; f < GK; f += 256) {
        int k = f / CC, c = f - k * CC;
        orow[f] = f2bf(s[c * KHH + k]);
    }
}

// ---------------- K2b: conv weights -> wcb[i][c] bf16 ----------------
__global__ __launch_bounds__(256) void k_wcb(const float* __restrict__ ow, const float* __restrict__ mw,
                                             unsigned short* __restrict__ wcb) {
    int i = blockIdx.x;
    for (int c = threadIdx.x; c < CC; c += 256) {
        float v = 0.f;
        if (i < 49)      v = ow[(size_t)(i / 7) * (CC * KHH) + (size_t)c * KHH + (i % 7)];
        else if (i < 98) { int j = i - 49; v = mw[(size_t)(j / 7) * (CC * KHH) + (size_t)c * KHH + (j % 7)]; }
        wcb[(size_t)i * CC + c] = f2bf(v);
    }
}

// ---------------- K3: d[row][i] = sum_c hb[row][c] * wcb[i][c] ----------------
__global__ __launch_bounds__(256) void k_dg2(const unsigned short* __restrict__ A,
        const unsigned short* __restrict__ Bm, float* __restrict__ d) {
    __shared__ __align__(16) char As[128 * 128];
    __shared__ __align__(16) char Bs[128 * 128];
    int r0 = blockIdx.x * 128;
    int t = threadIdx.x;
    int lane = t & 63, w = t >> 6;
    int wr = w >> 1, wc = w & 1;
    f32x4 acc[4][4];
#pragma unroll
    for (int m = 0; m < 4; ++m)
#pragma unroll
        for (int n = 0; n < 4; ++n) acc[m][n] = (f32x4){0.f, 0.f, 0.f, 0.f};
    int lr = lane & 15;
    int lkb0 = (lane >> 4) * 16;
    for (int kk = 0; kk < CC; kk += 64) {
#pragma unroll
        for (int s = 0; s < 4; ++s) {
            int byteoff = (s * 256 + t) * 16;
            int row = byteoff >> 7;
            int colb = byteoff & 127;
            int sw = (row * 128 + colb) ^ ((row & 7) << 4);
            *(ushort8*)(As + sw) = *(const ushort8*)(A + (size_t)(r0 + row) * CC + kk + (colb >> 1));
            *(ushort8*)(Bs + sw) = *(const ushort8*)(Bm + (size_t)row * CC + kk + (colb >> 1));
        }
        __syncthreads();
#pragma unroll
        for (int ks = 0; ks < 2; ++ks) {
            short8 av[4], bv[4];
            int lkb = lkb0 + ks * 64;
#pragma unroll
            for (int m = 0; m < 4; ++m) {
                int ar = wr * 64 + m * 16 + lr;
                av[m] = *(const short8*)(As + ((ar * 128 + lkb) ^ ((ar & 7) << 4)));
            }
#pragma unroll
            for (int n = 0; n < 4; ++n) {
                int br = wc * 64 + n * 16 + lr;
                bv[n] = *(const short8*)(Bs + ((br * 128 + lkb) ^ ((br & 7) << 4)));
            }
#pragma unroll
            for (int m = 0; m < 4; ++m)
#pragma unroll
                for (int n = 0; n < 4; ++n)
                    acc[m][n] = __builtin_amdgcn_mfma_f32_16x16x32_bf16(av[m], bv[n], acc[m][n], 0, 0, 0);
        }
        __syncthreads();
    }
    int lr4 = (lane >> 4) * 4, lc = lane & 15;
#pragma unroll
    for (int m = 0; m < 4; ++m) {
        int gr = r0 + wr * 64 + m * 16 + lr4;
#pragma unroll
        for (int n = 0; n < 4; ++n) {
            int gc = wc * 64 + n * 16 + lc;
#pragma unroll
            for (int j = 0; j < 4; ++j)
                d[(size_t)(gr + j) * 128 + gc] = acc[m][n][j];
        }
    }
}

// ---------------- K4: sampling params ----------------
__global__ __launch_bounds__(256) void k_off(const float* __restrict__ d,
        const float* __restrict__ offb, const float* __restrict__ modb,
        const float* __restrict__ gate,
        int* __restrict__ idx0, int* __restrict__ idx1,
        float* __restrict__ w0a, float* __restrict__ w1a) {
    int flat = blockIdx.x * 256 + threadIdx.x;   // b*7*L + k*L + p
    if (flat >= NKP) return;
    int p = flat & (LL - 1);
    int k = (flat >> 12) % KHH;
    int b = flat / (KHH * LL);
    float offa = offb[k], moda = modb[k];
#pragma unroll
    for (int j = 0; j < KHH; ++j) {
        int q = p + j - PADK;
        if (q >= 0 && q < LL) {
            const float* dr = d + (size_t)(b * LL + q) * 128;
            offa += dr[k * 7 + j];
            moda += dr[49 + k * 7 + j];
        }
    }
    float modv = 2.f / (1.f + expf(-moda));
    float pos = (float)(p - PADK + k) + offa;
    pos = fminf(fmaxf(pos, -1.0e9f), 1.0e9f);
    float f = floorf(pos);
    float tf = pos - f;
    int i0 = (int)f;
    int i1 = i0 + 1;
    float in0 = (i0 >= 0 && i0 < LL) ? 1.f : 0.f;
    float in1 = (i1 >= 0 && i1 < LL) ? 1.f : 0.f;
    int c0 = min(max(i0, 0), LL - 1);
    int c1 = min(max(i1, 0), LL - 1);
    float g0 = gate[b * LL + c0] * in0;
    float g1 = gate[b * LL + c1] * in1;
    w0a[flat] = modv * (1.f - tf) * g0;
    w1a[flat] = modv * tf * g1;
    idx0[flat] = c0;
    idx1[flat] = c1;
}

// ---------------- K5: fused sample+GEMM with async-STAGE split ----------------
// BM=128, BN=384, BK=64; 512 threads = 8 waves (2x4), wave tile 64x96 = 4x6 frags 16x16x32
// Per step: issue loads(s+1) -> compute(s) -> lerp+ds_write(s+1) -> barrier.
__global__ __launch_bounds__(512, 2) void k_fgemm(const unsigned short* __restrict__ hb,
        const unsigned short* __restrict__ Wb,
        const int* __restrict__ idx0, const int* __restrict__ idx1,
        const float* __restrict__ w0a, const float* __restrict__ w1a,
        const float* __restrict__ resid, float* __restrict__ out) {
    __shared__ __align__(16) char As[2][128 * 128];
    __shared__ __align__(16) char Bs[2][384 * 128];

    int bid = blockIdx.x;
    int nhalf = (bid & 7) >> 2;                 // XCDs 0-3 -> half 0, 4-7 -> half 1
    int rowtile = (bid >> 3) * 4 + (bid & 3);   // bijective 0..127
    int r0 = rowtile * 128;
    int o0 = nhalf * 384;
    int b = r0 >> 12;
    int p0 = r0 & (LL - 1);
    int pbase = ((b * KHH) << 12) + p0;
    const unsigned short* hbB = hb + (size_t)b * LL * CC;
    const unsigned short* wbase = Wb + (size_t)o0 * GK;

    int t = threadIdx.x;
    int lane = t & 63, w = t >> 6;
    int wr = w >> 2, wc = w & 3;

    // A-build mapping: row = t>>2 (0..127), seg = t&3 (16 elems each)
    int arow = t >> 2, aseg = t & 3;
    int acolb = aseg * 32;
    int aswz0 = arow * 128 + (acolb ^ ((arow & 7) << 4));
    int aswz1 = arow * 128 + ((acolb + 16) ^ ((arow & 7) << 4));

    f32x4 acc[4][6];
#pragma unroll
    for (int m = 0; m < 4; ++m)
#pragma unroll
        for (int n = 0; n < 6; ++n) acc[m][n] = (f32x4){0.f, 0.f, 0.f, 0.f};

    // per-tap sampling regs (constant for 12 consecutive K-steps)
    int g0 = 0, g1 = 0;
    float wa = 0.f, wbv = 0.f;
    int cur_tap = -1;

    // staging registers
    ushort8 la0, la1, la2, la3;
    ushort8 lb0, lb1, lb2, lb3, lb4, lb5;

    auto load_phase = [&](int tap, int c0) {
        if (tap != cur_tap) {
            int pf = pbase + (tap << 12) + arow;
            g0 = idx0[pf]; g1 = idx1[pf];
            wa = w0a[pf];  wbv = w1a[pf];
            cur_tap = tap;
        }
        const unsigned short* s0 = hbB + (size_t)g0 * CC + c0 + aseg * 16;
        const unsigned short* s1 = hbB + (size_t)g1 * CC + c0 + aseg * 16;
        la0 = *(const ushort8*)(s0);
        la1 = *(const ushort8*)(s0 + 8);
        la2 = *(const ushort8*)(s1);
        la3 = *(const ushort8*)(s1 + 8);
        int kk = tap * CC + c0;
        {
            int off0 = (0 * 512 + t) * 16;
            lb0 = *(const ushort8*)(wbase + (size_t)(off0 >> 7) * GK + kk + ((off0 & 127) >> 1));
            int off1 = (1 * 512 + t) * 16;
            lb1 = *(const ushort8*)(wbase + (size_t)(off1 >> 7) * GK + kk + ((off1 & 127) >> 1));
            int off2 = (2 * 512 + t) * 16;
            lb2 = *(const ushort8*)(wbase + (size_t)(off2 >> 7) * GK + kk + ((off2 & 127) >> 1));
            int off3 = (3 * 512 + t) * 16;
            lb3 = *(const ushort8*)(wbase + (size_t)(off3 >> 7) * GK + kk + ((off3 & 127) >> 1));
            int off4 = (4 * 512 + t) * 16;
            lb4 = *(const ushort8*)(wbase + (size_t)(off4 >> 7) * GK + kk + ((off4 & 127) >> 1));
            int off5 = (5 * 512 + t) * 16;
            lb5 = *(const ushort8*)(wbase + (size_t)(off5 >> 7) * GK + kk + ((off5 & 127) >> 1));
        }
    };

    auto write_phase = [&](char* Asb, char* Bsb) {
        ushort8 ra, rb;
#pragma unroll
        for (int e = 0; e < 8; ++e) ra[e] = f2bf(fmaf(wa, bf2f(la0[e]), wbv * bf2f(la2[e])));
#pragma unroll
        for (int e = 0; e < 8; ++e) rb[e] = f2bf(fmaf(wa, bf2f(la1[e]), wbv * bf2f(la3[e])));
        *(ushort8*)(Asb + aswz0) = ra;
        *(ushort8*)(Asb + aswz1) = rb;
#define BWR(i, lbv) { int off = (i * 512 + t) * 16; int brow = off >> 7; int colb = off & 127; \
        *(ushort8*)(Bsb + (brow * 128 + (colb ^ ((brow & 7) << 4)))) = lbv; }
        BWR(0, lb0) BWR(1, lb1) BWR(2, lb2) BWR(3, lb3) BWR(4, lb4) BWR(5, lb5)
#undef BWR
    };

    auto compute = [&](const char* Asb, const char* Bsb) {
        int lr = lane & 15;
        int lkb0 = (lane >> 4) * 16;
        __builtin_amdgcn_s_setprio(1);
#pragma unroll
        for (int ks = 0; ks < 2; ++ks) {
            short8 av[4], bv[6];
            int lkb = lkb0 + ks * 64;
#pragma unroll
            for (int m = 0; m < 4; ++m) {
                int ar = wr * 64 + m * 16 + lr;
                av[m] = *(const short8*)(Asb + ar * 128 + (lkb ^ ((ar & 7) << 4)));
            }
#pragma unroll
            for (int n = 0; n < 6; ++n) {
                int br = wc * 96 + n * 16 + lr;
                bv[n] = *(const short8*)(Bsb + br * 128 + (lkb ^ ((br & 7) << 4)));
            }
#pragma unroll
            for (int m = 0; m < 4; ++m)
#pragma unroll
                for (int n = 0; n < 6; ++n)
                    acc[m][n] = __builtin_amdgcn_mfma_f32_16x16x32_bf16(av[m], bv[n], acc[m][n], 0, 0, 0);
        }
        __builtin_amdgcn_s_setprio(0);
    };

    // prologue: stage step 0
    load_phase(0, 0);
    write_phase(As[0], Bs[0]);
    __syncthreads();

    int tap_n = 0, c0_n = 0;
    for (int s = 0; s < NT; ++s) {
        int cur = s & 1;
        c0_n += 64;
        if (c0_n == CC) { c0_n = 0; ++tap_n; }
        bool more = (s + 1 < NT);
        if (more) load_phase(tap_n, c0_n);          // issue loads, no use yet
        __builtin_amdgcn_sched_barrier(0);
        compute(As[cur], Bs[cur]);                  // MFMA hides load latency
        __builtin_amdgcn_sched_barrier(0);
        if (more) write_phase(As[cur ^ 1], Bs[cur ^ 1]);  // vmcnt wait happens here
        __syncthreads();
    }

    // epilogue: + residual
    int lr4 = (lane >> 4) * 4, lc = lane & 15;
#pragma unroll
    for (int m = 0; m < 4; ++m) {
        int gr = r0 + wr * 64 + m * 16 + lr4;
#pragma unroll
        for (int n = 0; n < 6; ++n) {
            int gc = o0 + wc * 96 + n * 16 + lc;
#pragma unroll
            for (int j = 0; j < 4; ++j) {
                size_t idx = (size_t)(gr + j) * CC + gc;
                out[idx] = acc[m][n][j] + resid[idx];
            }
        }
    }
}

extern "C" void kernel_launch(void* const* d_in, const int* in_sizes, int n_in,
                              void* d_out, int out_size, void* d_ws, size_t ws_size,
                              hipStream_t stream) {
    const float* x   = (const float*)d_in[0];
    const float* am  = (const float*)d_in[1];
    const float* stm = (const float*)d_in[2];
    const float* lnw = (const float*)d_in[3];
    const float* lnb = (const float*)d_in[4];
    const float* ow  = (const float*)d_in[5];
    const float* ob  = (const float*)d_in[6];
    const float* mw  = (const float*)d_in[7];
    const float* mb  = (const float*)d_in[8];
    const float* rw  = (const float*)d_in[9];
    float* out = (float*)d_out;

    char* ws = (char*)d_ws;
    size_t off = 0;
    auto carve = [&](size_t bytes) -> char* {
        char* p = ws + off;
        off += (bytes + 255) & ~(size_t)255;
        return p;
    };
    unsigned short* hb  = (unsigned short*)carve((size_t)ROWS * CC * 2);   // 25.2 MB
    unsigned short* wb  = (unsigned short*)carve((size_t)CC * GK * 2);     // 8.25 MB
    unsigned short* wcb = (unsigned short*)carve((size_t)128 * CC * 2);    // 0.20 MB
    float* d    = (float*)carve((size_t)ROWS * 128 * 4);                   // 8.4 MB
    float* gate = (float*)carve((size_t)ROWS * 4);
    int*   i0   = (int*)carve((size_t)NKP * 4);
    int*   i1   = (int*)carve((size_t)NKP * 4);
    float* w0   = (float*)carve((size_t)NKP * 4);
    float* w1   = (float*)carve((size_t)NKP * 4);

    k_ln<<<ROWS, 256, 0, stream>>>(x, am, stm, lnw, lnb, hb, gate);
    k_wb<<<CC, 256, 0, stream>>>(rw, wb);
    k_wcb<<<128, 256, 0, stream>>>(ow, mw, wcb);
    k_dg2<<<ROWS / 128, 256, 0, stream>>>(hb, wcb, d);
    k_off<<<NKP / 256, 256, 0, stream>>>(d, ob, mb, gate, i0, i1, w0, w1);
    k_fgemm<<<256, 512, 0, stream>>>(hb, wb, i0, i1, w0, w1, x, out);
}